// Round 22
// baseline (40.480 us; speedup 1.0000x reference)
//
#include <hip/hip_runtime.h>

#define DIM   256
#define CLS   512
#define NGF   32640          // packed strict-upper-triangle floats per class
#define NQ    8160           // NGF/4 float4 quads
#define NITER 4
#define YST   40             // y slice stride in h16 (80 B): banks {0,20,8,28,16,4,24,12}

typedef _Float16 h16;
typedef __attribute__((ext_vector_type(2))) _Float16 h16x2;

__device__ __forceinline__ float dot2f(unsigned a, unsigned b, float c) {
    return __builtin_amdgcn_fdot2(__builtin_bit_cast(h16x2, a),
                                  __builtin_bit_cast(h16x2, b), c, false);
}

__device__ __forceinline__ unsigned pkrtz(float lo, float hi) {
    return __builtin_bit_cast(unsigned, __builtin_amdgcn_cvt_pkrtz(lo, hi));
}

__device__ __forceinline__ uint2 cvt2(float4 v) {
    uint2 d;
    d.x = pkrtz(0.5f * v.x, 0.5f * v.y);
    d.y = pkrtz(0.5f * v.z, 0.5f * v.w);
    return d;
}

// barrier draining LDS only
__device__ __forceinline__ void bar_lds() {
    asm volatile("s_waitcnt lgkmcnt(0)\n\ts_barrier" ::: "memory");
}

// y[g] at (g>>5)*YST + (g&31)
__device__ __forceinline__ int yslot(int g) { return (g >> 5) * YST + (g & 31); }

// ---- gather one row's 32-col slice [32s, 32s+32) into sreg[16*RR .. +16) ----
#define GROW(RR, R, OFFR)                                                  \
    do {                                                                   \
        const int g0_ = 32 * s;                                            \
        if (g0_ > (R)) {                                                   \
            int au0_ = (OFFR) + g0_;                                       \
            unsigned d_[17];                                               \
            _Pragma("unroll")                                              \
            for (int i_ = 0; i_ < 17; ++i_) d_[i_] = Ud[(au0_ >> 1) + i_]; \
            const bool odd_ = (au0_ & 1);                                  \
            _Pragma("unroll")                                              \
            for (int i_ = 0; i_ < 16; ++i_) {                              \
                unsigned ev_ = d_[i_];                                     \
                unsigned od_ = __builtin_amdgcn_alignbit(d_[i_+1], d_[i_], 16); \
                sreg[16 * (RR) + i_] = odd_ ? od_ : ev_;                   \
            }                                                              \
        } else if (g0_ + 31 < (R)) {                                       \
            int g_  = g0_;                                                 \
            int al_ = ((g0_ * (511 - g0_)) >> 1) + (R) - g0_ - 1;          \
            unsigned wacc_ = 0;                                            \
            _Pragma("unroll")                                              \
            for (int t_ = 0; t_ < 32; ++t_) {                              \
                unsigned h_ = U[al_] ^ 0x8000u;                            \
                if (t_ & 1) { wacc_ |= h_ << 16; sreg[16*(RR)+(t_>>1)] = wacc_; } \
                else       { wacc_  = h_; }                                \
                al_ += 254 - g_;                                           \
                ++g_;                                                      \
            }                                                              \
        } else {                                                           \
            int g_  = g0_;                                                 \
            int au_ = (OFFR) + g0_;                                        \
            int al_ = ((g0_ * (511 - g0_)) >> 1) + (R) - g0_ - 1;          \
            unsigned wacc_ = 0;                                            \
            _Pragma("unroll")                                              \
            for (int t_ = 0; t_ < 32; ++t_) {                              \
                int idx_ = (g_ < (R)) ? al_ : au_;                         \
                idx_ = idx_ < 0 ? 0 : idx_;                                \
                unsigned h_ = U[idx_];                                     \
                h_ = (g_ < (R)) ? (h_ ^ 0x8000u) : h_;                     \
                h_ = (g_ == (R)) ? 0u : h_;                                \
                if (t_ & 1) { wacc_ |= h_ << 16; sreg[16*(RR)+(t_>>1)] = wacc_; } \
                else       { wacc_  = h_; }                                \
                ++au_;                                                     \
                al_ += 254 - g_;                                           \
                ++g_;                                                      \
            }                                                              \
        }                                                                  \
    } while (0)

__global__ void __launch_bounds__(1024)
cayley_kernel(const float* __restrict__ x, const float* __restrict__ W,
              float* __restrict__ out) {
    extern __shared__ char smem[];
    unsigned short* U  = (unsigned short*)smem;        // 65536 B: f16(0.5*W) packed triu
    unsigned*       Ud = (unsigned*)smem;
    uint2*          U2 = (uint2*)smem;
    h16* sy0 = (h16*)(smem + 65536);                   // 8*YST h16 = 640 B
    h16* sy1 = sy0 + 8 * YST;                          // 640 B

    const int tid = threadIdx.x;
    const int s   = tid & 7;         // col slice: [32s, 32s+32)
    const int rb  = tid >> 3;        // owns rows rb and rb+128
    const int r0  = rb;
    const int r1  = rb + 128;
    const int c   = blockIdx.x;
    const int offr0 = (r0 * (511 - r0)) / 2 - r0 - 1;
    const int offr1 = (r1 * (511 - r1)) / 2 - r1 - 1;

    // ===== stage packed W -> LDS as f16 (0.5*w), coalesced =====
    {
        const float4* Wc4 = (const float4*)(W + (size_t)c * NGF);
        #pragma unroll
        for (int k = 0; k < 7; ++k)
            U2[tid + 1024 * k] = cvt2(Wc4[tid + 1024 * k]);
        int q = tid + 7168;
        if (q < NQ) U2[q] = cvt2(Wc4[q]);
    }
    const float xr0 = x[(size_t)r0 * CLS + c];
    const float xr1 = x[(size_t)r1 * CLS + c];
    if (s == 0) {
        sy0[yslot(r0)] = (h16)xr0;
        sy0[yslot(r1)] = (h16)xr1;
    }
    __syncthreads();                                   // U + y0 visible

    // ===== gather both rows' slices into sreg, then PIN =====
    unsigned sreg[32];
    GROW(0, r0, offr0);
    GROW(1, r1, offr1);
    #pragma unroll
    for (int i = 0; i < 32; ++i) asm volatile("" : "+v"(sreg[i]));

    // ===== fixed-point iteration y <- x - S y ; out = x - 2 S y =====
    {
        h16* ycur = sy0;
        h16* ynxt = sy1;
        #pragma unroll
        for (int it = 0; it < NITER; ++it) {
            const uint4* yp = (const uint4*)(ycur + YST * s);
            uint4 y0 = yp[0], y1 = yp[1], y2 = yp[2], y3 = yp[3];
            // pin all 16 y-dwords: force one-shot materialization (VGPR >= ~58),
            // killing the register-starved per-batch lgkm chains of R20/R21
            asm volatile("" : "+v"(y0.x), "+v"(y0.y), "+v"(y0.z), "+v"(y0.w),
                              "+v"(y1.x), "+v"(y1.y), "+v"(y1.z), "+v"(y1.w),
                              "+v"(y2.x), "+v"(y2.y), "+v"(y2.z), "+v"(y2.w),
                              "+v"(y3.x), "+v"(y3.y), "+v"(y3.z), "+v"(y3.w));
            float a0, a1, a2, a3, b0, b1, b2, b3;
            a0 = dot2f(sreg[0],  y0.x, 0.f); a1 = dot2f(sreg[1],  y0.y, 0.f);
            a2 = dot2f(sreg[2],  y0.z, 0.f); a3 = dot2f(sreg[3],  y0.w, 0.f);
            a0 = dot2f(sreg[4],  y1.x, a0);  a1 = dot2f(sreg[5],  y1.y, a1);
            a2 = dot2f(sreg[6],  y1.z, a2);  a3 = dot2f(sreg[7],  y1.w, a3);
            a0 = dot2f(sreg[8],  y2.x, a0);  a1 = dot2f(sreg[9],  y2.y, a1);
            a2 = dot2f(sreg[10], y2.z, a2);  a3 = dot2f(sreg[11], y2.w, a3);
            a0 = dot2f(sreg[12], y3.x, a0);  a1 = dot2f(sreg[13], y3.y, a1);
            a2 = dot2f(sreg[14], y3.z, a2);  a3 = dot2f(sreg[15], y3.w, a3);
            b0 = dot2f(sreg[16], y0.x, 0.f); b1 = dot2f(sreg[17], y0.y, 0.f);
            b2 = dot2f(sreg[18], y0.z, 0.f); b3 = dot2f(sreg[19], y0.w, 0.f);
            b0 = dot2f(sreg[20], y1.x, b0);  b1 = dot2f(sreg[21], y1.y, b1);
            b2 = dot2f(sreg[22], y1.z, b2);  b3 = dot2f(sreg[23], y1.w, b3);
            b0 = dot2f(sreg[24], y2.x, b0);  b1 = dot2f(sreg[25], y2.y, b1);
            b2 = dot2f(sreg[26], y2.z, b2);  b3 = dot2f(sreg[27], y2.w, b3);
            b0 = dot2f(sreg[28], y3.x, b0);  b1 = dot2f(sreg[29], y3.y, b1);
            b2 = dot2f(sreg[30], y3.z, b2);  b3 = dot2f(sreg[31], y3.w, b3);
            float v0 = (a0 + a1) + (a2 + a3);          // partial (S y)_r0
            float v1 = (b0 + b1) + (b2 + b3);          // partial (S y)_r1
            v0 += __shfl_xor(v0, 1); v0 += __shfl_xor(v0, 2); v0 += __shfl_xor(v0, 4);
            v1 += __shfl_xor(v1, 1); v1 += __shfl_xor(v1, 2); v1 += __shfl_xor(v1, 4);
            if (it < NITER - 1) {
                if (s == 0) {
                    ynxt[yslot(r0)] = (h16)(xr0 - v0);
                    ynxt[yslot(r1)] = (h16)(xr1 - v1);
                }
                h16* t = ycur; ycur = ynxt; ynxt = t;
                bar_lds();
            } else if (s == 0) {
                out[(size_t)r0 * CLS + c] = xr0 - 2.f * v0;
                out[(size_t)r1 * CLS + c] = xr1 - 2.f * v1;
            }
        }
    }
}

extern "C" void kernel_launch(void* const* d_in, const int* in_sizes, int n_in,
                              void* d_out, int out_size, void* d_ws, size_t ws_size,
                              hipStream_t stream) {
    const float* x = (const float*)d_in[0];
    const float* W = (const float*)d_in[1];
    float* out = (float*)d_out;

    const size_t smem = 65536 + 2 * 8 * YST * 2;       // 66816 B -> 2 blocks/CU
    hipFuncSetAttribute((const void*)cayley_kernel,
                        hipFuncAttributeMaxDynamicSharedMemorySize, (int)smem);
    hipLaunchKernelGGL(cayley_kernel, dim3(CLS), dim3(1024), smem, stream, x, W, out);
}

// Round 23
// 26.622 us; speedup vs baseline: 1.5205x; 1.5205x over previous
//
#include <hip/hip_runtime.h>

#define DIM   256
#define CLS   512
#define NGF   32640          // packed strict-upper-triangle floats per class
#define NQ    8160           // NGF/4 float4 quads
#define NITER 3
#define PSH   72             // y part-slice stride in h16

typedef _Float16 h16;
typedef __attribute__((ext_vector_type(2))) _Float16 h16x2;

__device__ __forceinline__ float dot2f(unsigned a, unsigned b, float c) {
    return __builtin_amdgcn_fdot2(__builtin_bit_cast(h16x2, a),
                                  __builtin_bit_cast(h16x2, b), c, false);
}

__device__ __forceinline__ unsigned pkrtz(float lo, float hi) {
    return __builtin_bit_cast(unsigned, __builtin_amdgcn_cvt_pkrtz(lo, hi));
}

__device__ __forceinline__ uint2 cvt2(float4 v) {
    uint2 d;
    d.x = pkrtz(0.5f * v.x, 0.5f * v.y);
    d.y = pkrtz(0.5f * v.z, 0.5f * v.w);
    return d;
}

// barrier draining LDS only
__device__ __forceinline__ void bar_lds() {
    asm volatile("s_waitcnt lgkmcnt(0)\n\ts_barrier" ::: "memory");
}

// y[g] at part(g)*PSH + slot(g): part=(g>>4)&3, slot=((g>>6)<<4)|(g&15)
__device__ __forceinline__ int yaddr(int g) {
    return ((g >> 4) & 3) * PSH + (((g >> 6) << 4) | (g & 15));
}

__global__ void __launch_bounds__(1024)
cayley_kernel(const float* __restrict__ x, const float* __restrict__ W,
              float* __restrict__ out) {
    extern __shared__ char smem[];
    unsigned short* U  = (unsigned short*)smem;        // 65536 B: f16(0.5*W) packed triu
    unsigned*       Ud = (unsigned*)smem;
    uint2*          U2 = (uint2*)smem;
    h16* sy0 = (h16*)(smem + 65536);                   // 576 B
    h16* sy1 = sy0 + 4 * PSH;                          // 576 B

    const int tid  = threadIdx.x;
    const int r    = tid >> 2;       // row 0..255
    const int p    = tid & 3;        // part: owns columns {64a + 16p + t}
    const int c    = blockIdx.x;
    const int offr = (r * (511 - r)) / 2 - r - 1;      // off(r) - r - 1

    // ===== stage packed W -> LDS as f16 (0.5*w), coalesced =====
    {
        const float4* Wc4 = (const float4*)(W + (size_t)c * NGF);
        #pragma unroll
        for (int k = 0; k < 7; ++k)                    // q <= 7167 < NQ: unguarded
            U2[tid + 1024 * k] = cvt2(Wc4[tid + 1024 * k]);
        int q = tid + 7168;
        if (q < NQ) U2[q] = cvt2(Wc4[q]);
    }
    const float xr = x[(size_t)r * CLS + c];
    if (p == 0) sy0[yaddr(r)] = (h16)xr;
    __syncthreads();                                   // U + y0 visible

    // ===== gather S[r][g] for owned columns -> sreg (f16x2), 3-path =====
    unsigned sreg[32];
    {
        #pragma unroll
        for (int a = 0; a < 4; ++a) {
            const int g0 = 64 * a + 16 * p;
            if (g0 > r) {
                // ---- pure upper: contiguous U[au0..au0+15], vectorized ----
                int au0 = offr + g0;
                unsigned d[9];
                #pragma unroll
                for (int i = 0; i < 9; ++i) d[i] = Ud[(au0 >> 1) + i];
                const bool odd = (au0 & 1);
                #pragma unroll
                for (int i = 0; i < 8; ++i) {
                    unsigned ev = d[i];
                    unsigned od = __builtin_amdgcn_alignbit(d[i + 1], d[i], 16);
                    sreg[8 * a + i] = odd ? od : ev;
                }
            } else if (g0 + 15 < r) {
                // ---- pure lower: strided scalar, negate, no clamps ----
                int g  = g0;
                int al = ((g0 * (511 - g0)) >> 1) + r - g0 - 1;
                unsigned wacc = 0;
                #pragma unroll
                for (int t = 0; t < 16; ++t) {
                    unsigned h = U[al] ^ 0x8000u;
                    if (t & 1) { wacc |= h << 16; sreg[8 * a + (t >> 1)] = wacc; }
                    else       { wacc  = h; }
                    al += 254 - g;
                    ++g;
                }
            } else {
                // ---- mixed (contains diagonal): general scalar path ----
                int g  = g0;
                int au = offr + g0;
                int al = ((g0 * (511 - g0)) >> 1) + r - g0 - 1;
                unsigned wacc = 0;
                #pragma unroll
                for (int t = 0; t < 16; ++t) {
                    int idx = (g < r) ? al : au;
                    idx = idx < 0 ? 0 : idx;           // only r==g==0 hits -1
                    unsigned h = U[idx];
                    h = (g < r) ? (h ^ 0x8000u) : h;
                    h = (g == r) ? 0u : h;
                    if (t & 1) { wacc |= h << 16; sreg[8 * a + (t >> 1)] = wacc; }
                    else       { wacc  = h; }
                    ++au;
                    al += 254 - g;
                    ++g;
                }
            }
        }
    }

    // ===== fixed-point iteration y <- x - S y ; out = x - 2 S y =====
    {
        h16* ycur = sy0;
        h16* ynxt = sy1;
        const int wr = yaddr(r);
        #pragma unroll
        for (int it = 0; it < NITER; ++it) {
            const uint4* yp = (const uint4*)(ycur + p * PSH);
            float a0 = 0.f, a1 = 0.f, a2 = 0.f, a3 = 0.f;
            #pragma unroll
            for (int k = 0; k < 8; ++k) {
                uint4 yv = yp[k];
                a0 = dot2f(sreg[4 * k + 0], yv.x, a0);
                a1 = dot2f(sreg[4 * k + 1], yv.y, a1);
                a2 = dot2f(sreg[4 * k + 2], yv.z, a2);
                a3 = dot2f(sreg[4 * k + 3], yv.w, a3);
            }
            float v = (a0 + a1) + (a2 + a3);           // partial (S y)_r
            v += __shfl_xor(v, 1);
            v += __shfl_xor(v, 2);                     // full (S y)_r on 4 lanes
            if (it < NITER - 1) {
                if (p == 0) ynxt[wr] = (h16)(xr - v);
                h16* t = ycur; ycur = ynxt; ynxt = t;
                bar_lds();
            } else {
                if (p == 0) out[(size_t)r * CLS + c] = xr - 2.f * v;
            }
        }
    }
}

extern "C" void kernel_launch(void* const* d_in, const int* in_sizes, int n_in,
                              void* d_out, int out_size, void* d_ws, size_t ws_size,
                              hipStream_t stream) {
    const float* x = (const float*)d_in[0];
    const float* W = (const float*)d_in[1];
    float* out = (float*)d_out;

    const size_t smem = 65536 + 2 * 4 * PSH * 2;       // 66688 B -> 2 blocks/CU
    hipFuncSetAttribute((const void*)cayley_kernel,
                        hipFuncAttributeMaxDynamicSharedMemorySize, (int)smem);
    hipLaunchKernelGGL(cayley_kernel, dim3(CLS), dim3(1024), smem, stream, x, W, out);
}